// Round 1
// baseline (735.906 us; speedup 1.0000x reference)
//
#include <hip/hip_runtime.h>
#include <math.h>

#define NN 100000
#define NE 1600000
#define CC 64
#define ECH 32

// ---------------- Kernel 1: m = x @ W  ([N,64] @ [64,64]) ----------------
// W row-major [k][j]. Block = 256 threads handles 64 nodes; thread (j = t&63,
// g = t>>6) computes 16 nodes (g*16..g*16+15) for channel j. W staged in LDS,
// each weight reused 16x from a register.
__global__ __launch_bounds__(256) void k_xW(const float* __restrict__ x,
                                            const float* __restrict__ W,
                                            float* __restrict__ m) {
    __shared__ float xs[64][64];
    __shared__ float ws[64][64];
    const int t = threadIdx.x;
    const int j = t & 63;
    const int g = t >> 6;
    const int base = blockIdx.x * 64;
#pragma unroll
    for (int r = 0; r < 16; ++r) {
        int idx = r * 256 + t;
        ws[idx >> 6][idx & 63] = W[idx];
    }
#pragma unroll
    for (int r = 0; r < 16; ++r) {
        int idx = r * 256 + t;
        int n = idx >> 6, k = idx & 63;
        int gi = base + n;
        xs[n][k] = (gi < NN) ? x[gi * 64 + k] : 0.f;
    }
    __syncthreads();
    float acc[16];
#pragma unroll
    for (int q = 0; q < 16; ++q) acc[q] = 0.f;
    for (int k = 0; k < 64; ++k) {
        float w = ws[k][j];
#pragma unroll
        for (int q = 0; q < 16; ++q)
            acc[q] = fmaf(xs[g * 16 + q][k], w, acc[q]);
    }
#pragma unroll
    for (int q = 0; q < 16; ++q) {
        int n = base + g * 16 + q;
        if (n < NN) m[n * 64 + j] = acc[q];
    }
}

// ---------------- Kernel 2: edges ----------------
// One wave per edge. Lane j holds We[j][0..31] in 32 regs. Per edge:
// broadcast-load ea row (8x float4), 32 FMAs -> ew[j]; gather m[src][j];
// atomicAdd into agg[dst][j] (64 consecutive floats per wave).
__global__ __launch_bounds__(256) void k_edge(const float* __restrict__ ea,
                                              const int* __restrict__ eidx,
                                              const float* __restrict__ We,
                                              const float* __restrict__ m,
                                              float* __restrict__ agg) {
    const int lane = threadIdx.x & 63;
    const int wid = blockIdx.x * (blockDim.x >> 6) + (threadIdx.x >> 6);
    const int nw = gridDim.x * (blockDim.x >> 6);
    float4 w[8];
    const float4* wp = (const float4*)(We + lane * 32);
#pragma unroll
    for (int c = 0; c < 8; ++c) w[c] = wp[c];
    for (int e = wid; e < NE; e += nw) {
        int s = eidx[e];
        int d = eidx[NE + e];
        const float4* eap = (const float4*)(ea + (size_t)e * 32);
        float acc = 0.f;
#pragma unroll
        for (int c = 0; c < 8; ++c) {
            float4 v = eap[c];
            acc = fmaf(v.x, w[c].x, acc);
            acc = fmaf(v.y, w[c].y, acc);
            acc = fmaf(v.z, w[c].z, acc);
            acc = fmaf(v.w, w[c].w, acc);
        }
        float mg = m[(size_t)s * 64 + lane];
        atomicAdd(&agg[(size_t)d * 64 + lane], mg * acc);
    }
}

// ---------------- Kernel 3: GRU + epilogue ----------------
// gi = agg @ Wih^T + bih ; gh = x @ Whh^T + bhh ; gates; out = 0.5*relu(h)+0.5*x
// Block handles 64 nodes. Thread (j = t&63, g = t>>6) computes 16 nodes x 6
// gate pre-activations (96 f32 accumulators). Weights staged in k-chunks of 16
// transposed into LDS (padded rows to kill staging bank conflicts).
__global__ __launch_bounds__(256) void k_gru(const float* __restrict__ x,
                                             const float* __restrict__ agg,
                                             const float* __restrict__ Wih,
                                             const float* __restrict__ Whh,
                                             const float* __restrict__ bih,
                                             const float* __restrict__ bhh,
                                             float* __restrict__ out) {
    __shared__ float as_[64][64];
    __shared__ float xs[64][64];
    __shared__ float wi[16][193];
    __shared__ float wh[16][193];
    const int t = threadIdx.x;
    const int j = t & 63;
    const int g = t >> 6;
    const int base = blockIdx.x * 64;
#pragma unroll
    for (int r = 0; r < 16; ++r) {
        int idx = r * 256 + t;
        int n = idx >> 6, k = idx & 63;
        int gi = base + n;
        float av = 0.f, xv = 0.f;
        if (gi < NN) { av = agg[(size_t)gi * 64 + k]; xv = x[(size_t)gi * 64 + k]; }
        as_[n][k] = av;
        xs[n][k] = xv;
    }
    float ir[16], iz[16], inn[16], hr[16], hz[16], hn[16];
    float b0 = bih[j], b1 = bih[64 + j], b2 = bih[128 + j];
    float c0 = bhh[j], c1 = bhh[64 + j], c2 = bhh[128 + j];
#pragma unroll
    for (int q = 0; q < 16; ++q) {
        ir[q] = b0; iz[q] = b1; inn[q] = b2;
        hr[q] = c0; hz[q] = c1; hn[q] = c2;
    }
    for (int kc = 0; kc < 64; kc += 16) {
        __syncthreads();
#pragma unroll
        for (int r = 0; r < 12; ++r) {
            int idx = r * 256 + t;
            int row = idx >> 4, kk = idx & 15;
            wi[kk][row] = Wih[row * 64 + kc + kk];
            wh[kk][row] = Whh[row * 64 + kc + kk];
        }
        __syncthreads();
        for (int kk = 0; kk < 16; ++kk) {
            float wr = wi[kk][j], wz = wi[kk][64 + j], wn = wi[kk][128 + j];
            float vr = wh[kk][j], vz = wh[kk][64 + j], vn = wh[kk][128 + j];
#pragma unroll
            for (int q = 0; q < 16; ++q) {
                float a = as_[g * 16 + q][kc + kk];
                float xx = xs[g * 16 + q][kc + kk];
                ir[q] = fmaf(a, wr, ir[q]);
                iz[q] = fmaf(a, wz, iz[q]);
                inn[q] = fmaf(a, wn, inn[q]);
                hr[q] = fmaf(xx, vr, hr[q]);
                hz[q] = fmaf(xx, vz, hz[q]);
                hn[q] = fmaf(xx, vn, hn[q]);
            }
        }
    }
#pragma unroll
    for (int q = 0; q < 16; ++q) {
        int n = base + g * 16 + q;
        if (n < NN) {
            float r = 1.f / (1.f + __expf(-(ir[q] + hr[q])));
            float z = 1.f / (1.f + __expf(-(iz[q] + hz[q])));
            float nn = tanhf(inn[q] + r * hn[q]);
            float xv = xs[g * 16 + q][j];
            float h = (1.f - z) * nn + z * xv;
            float o = h > 0.f ? h : 0.f;
            out[(size_t)n * 64 + j] = 0.5f * o + 0.5f * xv;
        }
    }
}

extern "C" void kernel_launch(void* const* d_in, const int* in_sizes, int n_in,
                              void* d_out, int out_size, void* d_ws, size_t ws_size,
                              hipStream_t stream) {
    const float* x   = (const float*)d_in[0];
    const int*   ei  = (const int*)d_in[1];
    const float* ea  = (const float*)d_in[2];
    const float* We  = (const float*)d_in[3];
    const float* W   = (const float*)d_in[4];
    const float* Wih = (const float*)d_in[5];
    const float* Whh = (const float*)d_in[6];
    const float* bih = (const float*)d_in[7];
    const float* bhh = (const float*)d_in[8];
    float* out = (float*)d_out;

    float* m   = (float*)d_ws;                       // 25.6 MB
    float* agg = m + (size_t)NN * CC;                // 25.6 MB

    (void)in_sizes; (void)n_in; (void)out_size; (void)ws_size;

    int nb_nodes = (NN + 63) / 64;
    k_xW<<<nb_nodes, 256, 0, stream>>>(x, W, m);
    hipMemsetAsync(agg, 0, (size_t)NN * CC * sizeof(float), stream);
    k_edge<<<2048, 256, 0, stream>>>(ea, ei, We, m, agg);
    k_gru<<<nb_nodes, 256, 0, stream>>>(x, agg, Wih, Whh, bih, bhh, out);
}